// Round 1
// baseline (401.565 us; speedup 1.0000x reference)
//
#include <hip/hip_runtime.h>
#include <hip/hip_bf16.h>

typedef unsigned short ushort_t;
typedef __attribute__((ext_vector_type(8)))  short bf16x8;
typedef __attribute__((ext_vector_type(16))) float f32x16;

#define NB 16
#define NC 128
#define NO 128
#define NH 128
#define NW 128
#define NE 3

__device__ __forceinline__ ushort_t f2bf(float f) {
    __hip_bfloat16 h = __float2bfloat16(f);
    return *reinterpret_cast<ushort_t*>(&h);
}

__device__ __forceinline__ void gld_lds16(const void* g, void* l) {
    __builtin_amdgcn_global_load_lds(
        (const __attribute__((address_space(1))) unsigned int*)g,
        (__attribute__((address_space(3))) unsigned int*)l,
        16, 0, 0);
}

// ---------------- kernel 1: y mean over H*W per (b,c) ----------------
__global__ void mean_kernel(const float* __restrict__ y, float* __restrict__ yctx) {
    const int bc = blockIdx.x;                       // 0..2047
    const float4* p = (const float4*)(y + (size_t)bc * 16384);
    float s = 0.f;
    for (int i = threadIdx.x; i < 4096; i += 256) {
        float4 v = p[i];
        s += (v.x + v.y) + (v.z + v.w);
    }
#pragma unroll
    for (int off = 32; off > 0; off >>= 1) s += __shfl_down(s, off);
    __shared__ float red[4];
    const int wv = threadIdx.x >> 6, lane = threadIdx.x & 63;
    if (lane == 0) red[wv] = s;
    __syncthreads();
    if (threadIdx.x == 0)
        yctx[bc] = (red[0] + red[1] + red[2] + red[3]) * (1.f / 16384.f);
}

// ---------------- kernel 2: gates = softmax(yctx @ (gw[:C]+gw[C:]) + gb) ----------------
__global__ void gate_kernel(const float* __restrict__ yctx, const float* __restrict__ gw,
                            const float* __restrict__ gb, float* __restrict__ gates) {
    __shared__ float lg[NB][NE];
    const int t = threadIdx.x;   // 64 threads
    if (t < NB * NE) {
        const int b = t / NE, e = t % NE;
        float s = gb[e];
        const float* yc = yctx + b * NC;
        for (int c = 0; c < NC; ++c)
            s += yc[c] * (gw[c * NE + e] + gw[(c + NC) * NE + e]);
        lg[b][e] = s;
    }
    __syncthreads();
    if (t < NB) {
        float a0 = lg[t][0], a1 = lg[t][1], a2 = lg[t][2];
        float m = fmaxf(a0, fmaxf(a1, a2));
        float e0 = expf(a0 - m), e1 = expf(a1 - m), e2 = expf(a2 - m);
        float inv = 1.f / (e0 + e1 + e2);
        gates[t * 3 + 0] = e0 * inv;
        gates[t * 3 + 1] = e1 * inv;
        gates[t * 3 + 2] = e2 * inv;
    }
}

// ---------------- kernel 3: q[b][c][h][w] f32 -> qT[b][h][cg(16)][w(128)][8c] bf16 ----------------
__global__ void qtrans_kernel(const float* __restrict__ q, ushort_t* __restrict__ qT) {
    const int h = blockIdx.x, b = blockIdx.y;
    const int t = threadIdx.x;
    const int wseg = (t & 31) * 4;
#pragma unroll
    for (int ii = 0; ii < 2; ++ii) {
        const int cg = (t >> 5) + 8 * ii;
        float vt[8][4];
#pragma unroll
        for (int k = 0; k < 8; ++k) {
            float4 v = *(const float4*)(q + ((size_t)(b * NC + cg * 8 + k) * 16384 + h * NW + wseg));
            vt[k][0] = v.x; vt[k][1] = v.y; vt[k][2] = v.z; vt[k][3] = v.w;
        }
#pragma unroll
        for (int i = 0; i < 4; ++i) {
            unsigned int u[8];
#pragma unroll
            for (int k = 0; k < 8; ++k) u[k] = f2bf(vt[k][i]);
            uint4 pk;
            pk.x = u[0] | (u[1] << 16);
            pk.y = u[2] | (u[3] << 16);
            pk.z = u[4] | (u[5] << 16);
            pk.w = u[6] | (u[7] << 16);
            *(uint4*)&qT[(size_t)(b * NH + h) * 16384 + (size_t)(cg * 128 + wseg + i) * 8] = pk;
        }
    }
}

// ---------------- kernel 4: fold experts -> fragment-ordered bf16 weights ----------------
// wfrag layout: [b][cc(8)][m(4)][t(9)][lane(64)][j(8)] bf16, where for chunk cc:
//   lane&31 = o - m*32 ; lane>>5 = (c')>>3 ; j = c'&7 ; c' = c - cc*16
__global__ void wfold_kernel(const float* __restrict__ experts, const float* __restrict__ gates,
                             ushort_t* __restrict__ wfrag) {
    const int blk = blockIdx.x;                 // 512 blocks
    const int b = blk >> 5, cc = (blk >> 2) & 7, m = blk & 3;
    __shared__ __align__(16) ushort_t tile[9 * 64 * 8];
    const int t = threadIdx.x;
    float gg[3];
    gg[0] = gates[b * 3 + 0]; gg[1] = gates[b * 3 + 1]; gg[2] = gates[b * 3 + 2];
    const int obase = m * 32, cbase = cc * 16;
#pragma unroll
    for (int oi = 0; oi < 2; ++oi) {
        const int o = (t >> 4) + 16 * oi;       // 0..31
        const int c = (t & 15);                 // 0..15
        float w9[9];
#pragma unroll
        for (int k = 0; k < 9; ++k) w9[k] = 0.f;
#pragma unroll
        for (int e = 0; e < 3; ++e) {
            const float ge = gg[e];
            const float* p1 = experts + ((size_t)((e * NO) + obase + o) * 256 + cbase + c) * 9;
            const float* p2 = p1 + 128 * 9;
#pragma unroll
            for (int k = 0; k < 9; ++k) w9[k] += ge * (p1[k] + p2[k]);
        }
        const int lf = ((c >> 3) << 5) | o;
#pragma unroll
        for (int k = 0; k < 9; ++k) tile[(k * 64 + lf) * 8 + (c & 7)] = f2bf(w9[k]);
    }
    __syncthreads();
    ushort_t* dst = wfrag + (size_t)((b * 8 + cc) * 4 + m) * 4608;
    for (int u = t; u < 576; u += 256)
        ((uint4*)dst)[u] = ((const uint4*)tile)[u];
}

// ---------------- kernel 5: batched implicit-GEMM conv, 32x32x16 bf16 MFMA ----------------
// block: (b, h0=2*bx): 128 o x 256 px (2 rows). 4 waves; wave = 4 Mtiles x 2 Ntiles.
__global__ __launch_bounds__(256, 2)
void conv_kernel(const ushort_t* __restrict__ qT, const ushort_t* __restrict__ wfrag,
                 float* __restrict__ out) {
    const int b  = blockIdx.y;
    const int h0 = blockIdx.x * 2;
    const int tid  = threadIdx.x;
    const int wv   = tid >> 6;
    const int lane = tid & 63;
    const int l31  = lane & 31;
    const int g    = lane >> 5;

    __shared__ __align__(16) ushort_t A_lds[4 * 9 * 64 * 8];    // [m][t][lane][8]  36864 B
    __shared__ __align__(16) ushort_t q_lds[4 * 2 * 130 * 8];   // [qrow][g][col][8] 16640 B

    // zero halo columns (col 0 => w=-1, col 129 => w=128)
    if (tid < 16) {
        const int qr = tid >> 2, hg = (tid >> 1) & 1, cl = (tid & 1) * 129;
        uint4 zz; zz.x = zz.y = zz.z = zz.w = 0u;
        *(uint4*)&q_lds[((qr * 2 + hg) * 130 + cl) * 8] = zz;
    }

    f32x16 acc[4][2];
#pragma unroll
    for (int mi = 0; mi < 4; ++mi)
#pragma unroll
        for (int ni = 0; ni < 2; ++ni)
#pragma unroll
            for (int r = 0; r < 16; ++r) acc[mi][ni][r] = 0.f;

    const int qrow_s = wv;                  // this wave stages lds q-row wv
    const int hprime = h0 + qrow_s - 1;     // global h of that row
    const bool hvalid = (hprime >= 0) && (hprime < NH);

    for (int cc = 0; cc < 8; ++cc) {
        // stage A chunk: wave wv stages Mtile m = wv (9 taps x 1KB, linear)
        {
            const ushort_t* wb = wfrag + (size_t)(((b * 8 + cc) * 4 + wv)) * 4608;
#pragma unroll
            for (int t = 0; t < 9; ++t)
                gld_lds16(wb + (t * 64 + lane) * 8, &A_lds[((wv * 9 + t) * 64) * 8]);
        }
        // stage q row: wave wv stages qrow wv, both c-halves, 2x64 units each
        if (hvalid) {
            const ushort_t* qb = qT + (size_t)((b * NH + hprime) * 16 + cc * 2) * 1024;
#pragma unroll
            for (int hg = 0; hg < 2; ++hg)
#pragma unroll
                for (int it = 0; it < 2; ++it)
                    gld_lds16(qb + hg * 1024 + (it * 64 + lane) * 8,
                              &q_lds[((qrow_s * 2 + hg) * 130 + 1 + it * 64) * 8]);
        } else {
            uint4 zz; zz.x = zz.y = zz.z = zz.w = 0u;
#pragma unroll
            for (int hg = 0; hg < 2; ++hg)
#pragma unroll
                for (int it = 0; it < 2; ++it)
                    *(uint4*)&q_lds[((qrow_s * 2 + hg) * 130 + 1 + it * 64 + lane) * 8] = zz;
        }
        __syncthreads();

        // compute: 9 taps x (4 Mtiles x 2 Ntiles) MFMA, K=16 channels per chunk
#pragma unroll
        for (int kh = 0; kh < 3; ++kh) {
#pragma unroll
            for (int kw = 0; kw < 3; ++kw) {
                const int t = kh * 3 + kw;
                bf16x8 afr[4];
#pragma unroll
                for (int mi = 0; mi < 4; ++mi)
                    afr[mi] = *(const bf16x8*)&A_lds[((mi * 9 + t) * 64 + lane) * 8];
                bf16x8 bfr[2];
#pragma unroll
                for (int ni = 0; ni < 2; ++ni) {
                    const int n  = wv * 2 + ni;
                    const int r  = n >> 2;
                    const int w0 = (n & 3) * 32;
                    const int qrow = r + kh;
                    const int col  = w0 + l31 + kw;      // 0..129
                    bfr[ni] = *(const bf16x8*)&q_lds[((qrow * 2 + g) * 130 + col) * 8];
                }
#pragma unroll
                for (int mi = 0; mi < 4; ++mi)
#pragma unroll
                    for (int ni = 0; ni < 2; ++ni)
                        acc[mi][ni] = __builtin_amdgcn_mfma_f32_32x32x16_bf16(
                            afr[mi], bfr[ni], acc[mi][ni], 0, 0, 0);
            }
        }
        __syncthreads();
    }

    // epilogue: C/D map col=lane&31, row=(reg&3)+8*(reg>>2)+4*(lane>>5)
#pragma unroll
    for (int mi = 0; mi < 4; ++mi) {
#pragma unroll
        for (int ni = 0; ni < 2; ++ni) {
            const int n  = wv * 2 + ni;
            const int r  = n >> 2;
            const int w0 = (n & 3) * 32;
            const int hh = h0 + r;
            float* ob = out + ((size_t)(b * NO + mi * 32) * NH + hh) * NW + w0 + l31;
#pragma unroll
            for (int reg = 0; reg < 16; ++reg) {
                const int row = (reg & 3) + 8 * (reg >> 2) + 4 * g;
                ob[(size_t)row * (NH * NW)] = acc[mi][ni][reg];
            }
        }
    }
}

extern "C" void kernel_launch(void* const* d_in, const int* in_sizes, int n_in,
                              void* d_out, int out_size, void* d_ws, size_t ws_size,
                              hipStream_t stream) {
    (void)in_sizes; (void)n_in; (void)out_size; (void)ws_size;
    const float* q       = (const float*)d_in[0];
    const float* y       = (const float*)d_in[1];
    const float* experts = (const float*)d_in[2];
    const float* gate_w  = (const float*)d_in[3];
    const float* gate_b  = (const float*)d_in[4];
    float* out = (float*)d_out;

    char* ws = (char*)d_ws;
    float*    yctx  = (float*)ws;                         // 2048 f32
    float*    gates = (float*)(ws + 8192);                // 48 f32
    ushort_t* wfrag = (ushort_t*)(ws + 16384);            // 2,359,296 bf16 = 4.72 MB
    ushort_t* qT    = (ushort_t*)(ws + 4734976);          // 33.55M bf16 = 67.1 MB

    mean_kernel<<<2048, 256, 0, stream>>>(y, yctx);
    gate_kernel<<<1, 64, 0, stream>>>(yctx, gate_w, gate_b, gates);
    qtrans_kernel<<<dim3(NH, NB), 256, 0, stream>>>(q, qT);
    wfold_kernel<<<512, 256, 0, stream>>>(experts, gates, wfrag);
    conv_kernel<<<dim3(NH / 2, NB), 256, 0, stream>>>(qT, wfrag, out);
}

// Round 3
// 396.589 us; speedup vs baseline: 1.0125x; 1.0125x over previous
//
#include <hip/hip_runtime.h>
#include <hip/hip_bf16.h>

typedef unsigned short ushort_t;
typedef __attribute__((ext_vector_type(8)))  short bf16x8;
typedef __attribute__((ext_vector_type(16))) float f32x16;

#define NB 16
#define NC 128
#define NO 128
#define NH 128
#define NW 128
#define NE 3

__device__ __forceinline__ ushort_t f2bf(float f) {
    __hip_bfloat16 h = __float2bfloat16(f);
    return *reinterpret_cast<ushort_t*>(&h);
}

__device__ __forceinline__ void gld_lds16(const void* g, void* l) {
    __builtin_amdgcn_global_load_lds(
        (const __attribute__((address_space(1))) unsigned int*)g,
        (__attribute__((address_space(3))) unsigned int*)l,
        16, 0, 0);
}

// ---------------- kernel 1: y mean over H*W per (b,c) ----------------
__global__ void mean_kernel(const float* __restrict__ y, float* __restrict__ yctx) {
    const int bc = blockIdx.x;                       // 0..2047
    const float4* p = (const float4*)(y + (size_t)bc * 16384);
    float s = 0.f;
    for (int i = threadIdx.x; i < 4096; i += 256) {
        float4 v = p[i];
        s += (v.x + v.y) + (v.z + v.w);
    }
#pragma unroll
    for (int off = 32; off > 0; off >>= 1) s += __shfl_down(s, off);
    __shared__ float red[4];
    const int wv = threadIdx.x >> 6, lane = threadIdx.x & 63;
    if (lane == 0) red[wv] = s;
    __syncthreads();
    if (threadIdx.x == 0)
        yctx[bc] = (red[0] + red[1] + red[2] + red[3]) * (1.f / 16384.f);
}

// ---------------- kernel 2: gates = softmax(yctx @ (gw[:C]+gw[C:]) + gb) ----------------
__global__ void gate_kernel(const float* __restrict__ yctx, const float* __restrict__ gw,
                            const float* __restrict__ gb, float* __restrict__ gates) {
    __shared__ float lg[NB][NE];
    const int t = threadIdx.x;   // 64 threads
    if (t < NB * NE) {
        const int b = t / NE, e = t % NE;
        float s = gb[e];
        const float* yc = yctx + b * NC;
        for (int c = 0; c < NC; ++c)
            s += yc[c] * (gw[c * NE + e] + gw[(c + NC) * NE + e]);
        lg[b][e] = s;
    }
    __syncthreads();
    if (t < NB) {
        float a0 = lg[t][0], a1 = lg[t][1], a2 = lg[t][2];
        float m = fmaxf(a0, fmaxf(a1, a2));
        float e0 = expf(a0 - m), e1 = expf(a1 - m), e2 = expf(a2 - m);
        float inv = 1.f / (e0 + e1 + e2);
        gates[t * 3 + 0] = e0 * inv;
        gates[t * 3 + 1] = e1 * inv;
        gates[t * 3 + 2] = e2 * inv;
    }
}

// ---------------- kernel 3: q[b][c][h][w] f32 -> qT[b][h][cg(16)][w(128)][8c] bf16 ----------------
// scalar-gather: per 16B output unit, 8 coalesced 4B lane loads; stores 1KB/wave contiguous
__global__ void qtrans_kernel(const float* __restrict__ q, ushort_t* __restrict__ qT) {
    const int h = blockIdx.x, b = blockIdx.y;
    const int t = threadIdx.x;
    const float* qb = q + (size_t)b * NC * 16384 + h * NW;
    ushort_t* dst = qT + (size_t)(b * NH + h) * 16384;
#pragma unroll
    for (int kk = 0; kk < 8; ++kk) {
        const int u = t + 256 * kk;          // unit id 0..2047
        const int cg = u >> 7, w = u & 127;
        const float* p = qb + (size_t)(cg * 8) * 16384 + w;
        unsigned int uu[8];
#pragma unroll
        for (int j = 0; j < 8; ++j) uu[j] = f2bf(p[(size_t)j * 16384]);
        uint4 pk;
        pk.x = uu[0] | (uu[1] << 16);
        pk.y = uu[2] | (uu[3] << 16);
        pk.z = uu[4] | (uu[5] << 16);
        pk.w = uu[6] | (uu[7] << 16);
        *(uint4*)&dst[(size_t)u * 8] = pk;
    }
}

// ---------------- kernel 4: fold experts -> fragment-ordered bf16 weights ----------------
// wfrag layout: [b][cc(8)][m(4)][t(9)][lane(64)][j(8)] bf16:
//   lane&31 = o - m*32 ; lane>>5 = (c')>>3 ; j = c'&7 ; c' = c - cc*16
__global__ void wfold_kernel(const float* __restrict__ experts, const float* __restrict__ gates,
                             ushort_t* __restrict__ wfrag) {
    const int blk = blockIdx.x;                 // 512 blocks
    const int b = blk >> 5, cc = (blk >> 2) & 7, m = blk & 3;
    __shared__ __align__(16) ushort_t tile[9 * 64 * 8];
    const int t = threadIdx.x;
    float gg[3];
    gg[0] = gates[b * 3 + 0]; gg[1] = gates[b * 3 + 1]; gg[2] = gates[b * 3 + 2];
    const int obase = m * 32, cbase = cc * 16;
#pragma unroll
    for (int oi = 0; oi < 2; ++oi) {
        const int o = (t >> 4) + 16 * oi;       // 0..31
        const int c = (t & 15);                 // 0..15
        float w9[9];
#pragma unroll
        for (int k = 0; k < 9; ++k) w9[k] = 0.f;
#pragma unroll
        for (int e = 0; e < 3; ++e) {
            const float ge = gg[e];
            const float* p1 = experts + ((size_t)((e * NO) + obase + o) * 256 + cbase + c) * 9;
            const float* p2 = p1 + 128 * 9;
#pragma unroll
            for (int k = 0; k < 9; ++k) w9[k] += ge * (p1[k] + p2[k]);
        }
        const int lf = ((c >> 3) << 5) | o;
#pragma unroll
        for (int k = 0; k < 9; ++k) tile[(k * 64 + lf) * 8 + (c & 7)] = f2bf(w9[k]);
    }
    __syncthreads();
    ushort_t* dst = wfrag + (size_t)((b * 8 + cc) * 4 + m) * 4608;
    for (int u = t; u < 576; u += 256)
        ((uint4*)dst)[u] = ((const uint4*)tile)[u];
}

// ---------------- kernel 5: batched implicit-GEMM conv, 32x32x16 bf16 MFMA ----------------
// block: (b, h0, mhalf): 64 o x 256 px (2 rows). 4 waves; wave = 1 Mtile x 4 Ntiles (acc=64 VGPR).
// XCD swizzle: lid&7 = xcd, b slowest -> per-XCD qT working set ~0.9MB (L2-resident halo reuse).
__global__ __launch_bounds__(256, 4)
void conv_kernel(const ushort_t* __restrict__ qT, const ushort_t* __restrict__ wfrag,
                 float* __restrict__ out) {
    const int lid = blockIdx.x;          // 0..2047
    const int xcd = lid & 7;
    const int r   = lid >> 3;            // 0..255
    const int b   = r >> 4;              // slowest
    const int s   = r & 15;
    const int mhalf = s & 1;
    const int h0  = (xcd * 8 + (s >> 1)) * 2;   // 0..126 even

    const int tid  = threadIdx.x;
    const int wv   = tid >> 6;
    const int lane = tid & 63;
    const int l31  = lane & 31;
    const int g    = lane >> 5;

    __shared__ __align__(16) ushort_t A_lds[2 * 9 * 64 * 8];    // [m2][t][lane][8]  18432 B
    __shared__ __align__(16) ushort_t q_lds[4 * 2 * 130 * 8];   // [qrow][hg][col][8] 16640 B

    // zero halo columns (col 0 => w=-1, col 129 => w=128)
    if (tid < 16) {
        const int qr = tid >> 2, hg = (tid >> 1) & 1, cl = (tid & 1) * 129;
        uint4 zz; zz.x = zz.y = zz.z = zz.w = 0u;
        *(uint4*)&q_lds[((qr * 2 + hg) * 130 + cl) * 8] = zz;
    }

    f32x16 acc[4];
#pragma unroll
    for (int j = 0; j < 4; ++j)
#pragma unroll
        for (int rr = 0; rr < 16; ++rr) acc[j][rr] = 0.f;

    const int myM = wv >> 1;            // Mtile within half (0..1)
    const int ng  = wv & 1;             // output row within block (0..1)

    const int hp = h0 + wv - 1;         // q-row this wave stages (lds row wv)
    const bool hvalid = (hp >= 0) && (hp < NH);

    for (int cc = 0; cc < 8; ++cc) {
        // stage A: waves 0,1 stage Mtile (mhalf*2 + wv), 9 taps x 1KB linear
        if (wv < 2) {
            const ushort_t* wb = wfrag + (size_t)((b * 8 + cc) * 4 + mhalf * 2 + wv) * 4608;
#pragma unroll
            for (int t = 0; t < 9; ++t)
                gld_lds16(wb + (t * 64 + lane) * 8, &A_lds[((wv * 9 + t) * 64) * 8]);
        }
        // stage q: wave wv stages lds row wv (global row hp), 2 cg-halves x 2 segments
        if (hvalid) {
            const ushort_t* qb = qT + (size_t)(b * NH + hp) * 16384 + cc * 2048;
#pragma unroll
            for (int hg = 0; hg < 2; ++hg)
#pragma unroll
                for (int it = 0; it < 2; ++it)
                    gld_lds16(qb + hg * 1024 + (it * 64 + lane) * 8,
                              &q_lds[((wv * 2 + hg) * 130 + 1 + it * 64) * 8]);
        } else {
            uint4 zz; zz.x = zz.y = zz.z = zz.w = 0u;
#pragma unroll
            for (int hg = 0; hg < 2; ++hg)
#pragma unroll
                for (int it = 0; it < 2; ++it)
                    *(uint4*)&q_lds[((wv * 2 + hg) * 130 + 1 + it * 64 + lane) * 8] = zz;
        }
        __syncthreads();

        // compute: 9 taps x 4 Ntiles, K=16 channels per chunk
#pragma unroll
        for (int kh = 0; kh < 3; ++kh) {
#pragma unroll
            for (int kw = 0; kw < 3; ++kw) {
                const int t = kh * 3 + kw;
                bf16x8 afr = *(const bf16x8*)&A_lds[((myM * 9 + t) * 64 + lane) * 8];
#pragma unroll
                for (int j = 0; j < 4; ++j) {
                    const int col = j * 32 + l31 + kw;              // 0..129
                    bf16x8 bfr = *(const bf16x8*)&q_lds[(((ng + kh) * 2 + g) * 130 + col) * 8];
                    acc[j] = __builtin_amdgcn_mfma_f32_32x32x16_bf16(afr, bfr, acc[j], 0, 0, 0);
                }
            }
        }
        __syncthreads();
    }

    // epilogue: C/D map col=lane&31, row=(reg&3)+8*(reg>>2)+4*(lane>>5)
    const int obase = mhalf * 64 + myM * 32;
    const int hh = h0 + ng;
#pragma unroll
    for (int j = 0; j < 4; ++j) {
        float* ob = out + ((size_t)(b * NO + obase) * NH + hh) * NW + j * 32 + l31;
#pragma unroll
        for (int reg = 0; reg < 16; ++reg) {
            const int row = (reg & 3) + 8 * (reg >> 2) + 4 * g;
            ob[(size_t)row * (NH * NW)] = acc[j][reg];
        }
    }
}

extern "C" void kernel_launch(void* const* d_in, const int* in_sizes, int n_in,
                              void* d_out, int out_size, void* d_ws, size_t ws_size,
                              hipStream_t stream) {
    (void)in_sizes; (void)n_in; (void)out_size; (void)ws_size;
    const float* q       = (const float*)d_in[0];
    const float* y       = (const float*)d_in[1];
    const float* experts = (const float*)d_in[2];
    const float* gate_w  = (const float*)d_in[3];
    const float* gate_b  = (const float*)d_in[4];
    float* out = (float*)d_out;

    char* ws = (char*)d_ws;
    float*    yctx  = (float*)ws;                         // 2048 f32
    float*    gates = (float*)(ws + 8192);                // 48 f32
    ushort_t* wfrag = (ushort_t*)(ws + 16384);            // 2,359,296 bf16 = 4.72 MB
    ushort_t* qT    = (ushort_t*)(ws + 4734976);          // 33.55M bf16 = 67.1 MB

    mean_kernel<<<2048, 256, 0, stream>>>(y, yctx);
    gate_kernel<<<1, 64, 0, stream>>>(yctx, gate_w, gate_b, gates);
    qtrans_kernel<<<dim3(NH, NB), 256, 0, stream>>>(q, qT);
    wfold_kernel<<<512, 256, 0, stream>>>(experts, gates, wfrag);
    conv_kernel<<<2048, 256, 0, stream>>>(qT, wfrag, out);
}